// Round 1
// baseline (294.521 us; speedup 1.0000x reference)
//
#include <hip/hip_runtime.h>

#define BB 32
#define TT 1024
#define NN 128

// DPP row_ror:N add — 16-lane rotation reduce, pure VALU (no ds_swizzle waits).
// row_ror ctrl = 0x120 | N (gfx9+ DPP encoding); row = 16 lanes on CDNA.
#define ROR_ADD(p, ctrl)                                                      \
  p += __int_as_float(__builtin_amdgcn_update_dpp(                            \
      0, __float_as_int(p), ctrl, 0xF, 0xF, true));

__global__ __launch_bounds__(256)
void bdh_seq_kernel(const float* __restrict__ x,
                    const float* __restrict__ w_init,
                    const float* __restrict__ alpha_p,
                    const float* __restrict__ eta_p,
                    const int*   __restrict__ mask,
                    float* __restrict__ out)
{
    const int tid  = threadIdx.x;
    const int bidx = blockIdx.x;
    // b = bidx%32 keeps a batch's 8 blocks on one XCD (L2 locality for x).
    const int b      = bidx & 31;
    const int i_base = (bidx >> 5) << 4;   // 16 rows per block
    const int row    = tid >> 4;           // 0..15 (4 rows per wave)
    const int cg     = tid & 15;           // 16 lanes per row
    const int i      = i_base + row;       // global row 0..127
    const int j0     = cg << 3;            // 8 cols per lane

    const float alpha = alpha_p[0];
    const float eta   = eta_p[0];

    const float* xb = x + (size_t)b * TT * NN;
    const int*   mb = mask + b * TT;

    float* out_w = out + ((size_t)b * NN + i) * NN + j0;
    float* ybase = out + (size_t)BB * NN * NN + (size_t)b * TT * NN + i;

    const float* wrow = w_init + ((size_t)b * NN + i) * NN + j0;
    float4 w0 = *reinterpret_cast<const float4*>(wrow);
    float4 w1 = *reinterpret_cast<const float4*>(wrow + 4);

    // 2-deep software pipeline for x/mask (1 wave/SIMD: stalls are not hidden
    // by other waves, so prefetch distance must cover L1/L2 latency).
    float4 xA0 = *reinterpret_cast<const float4*>(xb + j0);
    float4 xA1 = *reinterpret_cast<const float4*>(xb + j0 + 4);
    float  xiA = xb[i];
    int    mA  = mb[0];
    float4 xB0 = *reinterpret_cast<const float4*>(xb + NN + j0);
    float4 xB1 = *reinterpret_cast<const float4*>(xb + NN + j0 + 4);
    float  xiB = xb[NN + i];
    int    mB  = mb[1];

#define STEP(tt, X0, X1, XI, MM, TNEXT)                                       \
  {                                                                           \
    const float aa = MM ? alpha : 1.0f;                                       \
    const float ee = MM ? eta   : 0.0f;                                       \
    const float ci = ee * XI;                                                 \
    /* y = W_{t-1} x_t : dot over this lane's 8 columns (read w BEFORE upd) */\
    float pa = w0.x * X0.x;                                                   \
    pa = fmaf(w0.y, X0.y, pa);                                                \
    pa = fmaf(w0.z, X0.z, pa);                                                \
    pa = fmaf(w0.w, X0.w, pa);                                                \
    float pb = w1.x * X1.x;                                                   \
    pb = fmaf(w1.y, X1.y, pb);                                                \
    pb = fmaf(w1.z, X1.z, pb);                                                \
    pb = fmaf(w1.w, X1.w, pb);                                                \
    float p = pa + pb;                                                        \
    /* masked update: m? alpha*w + (eta*xi)*xj : w  (aa=1,ci=0 when m==0) */  \
    w0.x = fmaf(aa, w0.x, ci * X0.x);                                         \
    w0.y = fmaf(aa, w0.y, ci * X0.y);                                         \
    w0.z = fmaf(aa, w0.z, ci * X0.z);                                         \
    w0.w = fmaf(aa, w0.w, ci * X0.w);                                         \
    w1.x = fmaf(aa, w1.x, ci * X1.x);                                         \
    w1.y = fmaf(aa, w1.y, ci * X1.y);                                         \
    w1.z = fmaf(aa, w1.z, ci * X1.z);                                         \
    w1.w = fmaf(aa, w1.w, ci * X1.w);                                         \
    /* prefetch x/mask two steps ahead (branchless clamp keeps loads legal) */\
    {                                                                         \
      int tn = (TNEXT) < TT ? (TNEXT) : (TT - 1);                             \
      const float* pn = xb + (size_t)tn * NN;                                 \
      X0 = *reinterpret_cast<const float4*>(pn + j0);                         \
      X1 = *reinterpret_cast<const float4*>(pn + j0 + 4);                     \
      XI = pn[i];                                                             \
      MM = mb[tn];                                                            \
    }                                                                         \
    /* 16-lane rotation reduce; all lanes end with the full sum */            \
    ROR_ADD(p, 0x121);                                                        \
    ROR_ADD(p, 0x122);                                                        \
    ROR_ADD(p, 0x124);                                                        \
    ROR_ADD(p, 0x128);                                                        \
    if (cg == 0) ybase[(size_t)(tt) * NN] = p;                                \
  }

#pragma unroll 1
    for (int t = 0; t < TT; t += 2) {
        STEP(t,     xA0, xA1, xiA, mA, t + 2);
        STEP(t + 1, xB0, xB1, xiB, mB, t + 3);
    }
#undef STEP

    *reinterpret_cast<float4*>(out_w)     = w0;
    *reinterpret_cast<float4*>(out_w + 4) = w1;
}

extern "C" void kernel_launch(void* const* d_in, const int* in_sizes, int n_in,
                              void* d_out, int out_size, void* d_ws, size_t ws_size,
                              hipStream_t stream)
{
    const float* x      = (const float*)d_in[0];
    const float* w_init = (const float*)d_in[1];
    const float* alpha  = (const float*)d_in[2];
    const float* eta    = (const float*)d_in[3];
    const int*   mask   = (const int*)d_in[4];
    float*       out    = (float*)d_out;

    dim3 grid(256), block(256);
    hipLaunchKernelGGL(bdh_seq_kernel, grid, block, 0, stream,
                       x, w_init, alpha, eta, mask, out);
}

// Round 2
// 230.900 us; speedup vs baseline: 1.2755x; 1.2755x over previous
//
#include <hip/hip_runtime.h>

#define BB 32
#define TT 1024
#define NN 128
#define YB 256   // y steps buffered in LDS between flushes

// DPP cross-lane adds (pure VALU — keeps cross-lane work off lgkm/vm counters).
#define ROR_ADD(p, ctrl)                                                      \
  p += __int_as_float(__builtin_amdgcn_update_dpp(                            \
      0, __float_as_int(p), ctrl, 0xF, 0xF, true));
// row_bcast15 (0x142): lane15 -> lanes16-31, lane47 -> lanes48-63.
// After 4x row_ror the two 16-lane half-sums combine; full row sum lands in
// lanes 16-31 (row A of the wave) and 48-63 (row B). Writer = lane16/48.
#define BCAST15_ADD(p)                                                        \
  p += __int_as_float(__builtin_amdgcn_update_dpp(                            \
      0, __float_as_int(p), 0x142, 0xF, 0xF, true));

__global__ __launch_bounds__(256)
void bdh_seq_kernel(const float* __restrict__ x,
                    const float* __restrict__ w_init,
                    const float* __restrict__ alpha_p,
                    const float* __restrict__ eta_p,
                    const int*   __restrict__ mask,
                    float* __restrict__ out)
{
    const int tid  = threadIdx.x;
    const int bidx = blockIdx.x;           // 512 blocks
    const int b      = bidx & 31;          // same-batch blocks land on one XCD (%8)
    const int i_base = (bidx >> 5) << 3;   // 8 rows per block
    const int rloc   = tid >> 5;           // 0..7 local row (32 lanes per row)
    const int i      = i_base + rloc;
    const int cg     = tid & 31;
    const int j0     = cg << 2;            // 4 cols per lane

    __shared__ float ybuf[YB][8];

    const float alpha = alpha_p[0];
    const float eta   = eta_p[0];

    const float* xb   = x + (size_t)b * TT * NN;
    const float* xcol = xb + j0;
    const int*   mb   = mask + b * TT;

    float* wout = out + ((size_t)b * NN + i) * NN + j0;
    float* yout = out + (size_t)BB * NN * NN + (size_t)b * TT * NN;

    float4 w = *reinterpret_cast<const float4*>(
        w_init + ((size_t)b * NN + i) * NN + j0);

    // 4-deep software pipeline for x / x[i] / mask.
    float4 XA = *reinterpret_cast<const float4*>(xcol + 0 * NN);
    float4 XB = *reinterpret_cast<const float4*>(xcol + 1 * NN);
    float4 XC = *reinterpret_cast<const float4*>(xcol + 2 * NN);
    float4 XD = *reinterpret_cast<const float4*>(xcol + 3 * NN);
    float xiA = xb[0 * NN + i], xiB = xb[1 * NN + i];
    float xiC = xb[2 * NN + i], xiD = xb[3 * NN + i];
    int   mA_ = mb[0], mB_ = mb[1], mC_ = mb[2], mD_ = mb[3];

#define STEP(tt, X, XI, MM, TNEXT)                                            \
  {                                                                           \
    const float aa = MM ? alpha : 1.0f;                                       \
    const float ci = (MM ? eta : 0.0f) * XI;                                  \
    /* y contribution: dot over this lane's 4 cols (read w BEFORE update) */  \
    float p0 = fmaf(w.y, X.y, w.x * X.x);                                     \
    float p1 = fmaf(w.w, X.w, w.z * X.z);                                     \
    float p  = p0 + p1;                                                       \
    /* masked Hebbian update (aa=1, ci=0 when mask==0) */                     \
    w.x = fmaf(aa, w.x, ci * X.x);                                            \
    w.y = fmaf(aa, w.y, ci * X.y);                                            \
    w.z = fmaf(aa, w.z, ci * X.z);                                            \
    w.w = fmaf(aa, w.w, ci * X.w);                                            \
    /* prefetch 4 steps ahead (branchless clamp keeps loads in-bounds) */     \
    {                                                                         \
      int tn = (TNEXT) < TT ? (TNEXT) : (TT - 1);                             \
      const float* pn = xb + (size_t)tn * NN;                                 \
      X  = *reinterpret_cast<const float4*>(pn + j0);                         \
      XI = pn[i];                                                             \
      MM = mb[tn];                                                            \
    }                                                                         \
    /* 32-lane reduce: 4x ror within 16, bcast15 to combine halves */        \
    ROR_ADD(p, 0x121);                                                        \
    ROR_ADD(p, 0x122);                                                        \
    ROR_ADD(p, 0x124);                                                        \
    ROR_ADD(p, 0x128);                                                        \
    BCAST15_ADD(p);                                                           \
    /* y goes to LDS (lgkm), NOT global — keeps stores off the vmcnt path */  \
    if ((tid & 31) == 16) ybuf[(tt) & (YB - 1)][rloc] = p;                    \
  }

#pragma unroll 1
    for (int t = 0; t < TT; t += 4) {
        STEP(t + 0, XA, xiA, mA_, t + 4);
        STEP(t + 1, XB, xiB, mB_, t + 5);
        STEP(t + 2, XC, xiC, mC_, t + 6);
        STEP(t + 3, XD, xiD, mD_, t + 7);
        // Flush 256 buffered y steps with coalesced stores (4x per kernel).
        if ((t & (YB - 1)) == YB - 4) {
            __syncthreads();
            const int t0 = t + 4 - YB;
#pragma unroll
            for (int pass = 0; pass < 8; ++pass) {
                const int tq = (tid >> 3) + (pass << 5);
                const int il = tid & 7;
                yout[(size_t)(t0 + tq) * NN + i_base + il] = ybuf[tq][il];
            }
            __syncthreads();
        }
    }
#undef STEP

    *reinterpret_cast<float4*>(wout) = w;
}

extern "C" void kernel_launch(void* const* d_in, const int* in_sizes, int n_in,
                              void* d_out, int out_size, void* d_ws, size_t ws_size,
                              hipStream_t stream)
{
    const float* x      = (const float*)d_in[0];
    const float* w_init = (const float*)d_in[1];
    const float* alpha  = (const float*)d_in[2];
    const float* eta    = (const float*)d_in[3];
    const int*   mask   = (const int*)d_in[4];
    float*       out    = (float*)d_out;

    dim3 grid(512), block(256);
    hipLaunchKernelGGL(bdh_seq_kernel, grid, block, 0, stream,
                       x, w_init, alpha, eta, mask, out);
}

// Round 4
// 185.060 us; speedup vs baseline: 1.5915x; 1.2477x over previous
//
#include <hip/hip_runtime.h>

#define BB 32
#define TT 1024
#define NN 128
#define YB 256   // y steps buffered in LDS between flushes

// DPP row_ror:N add — 16-lane rotation reduce, pure VALU. ctrl must be a
// compile-time literal (front-end constraint), hence explicit stages below.
#define ROR_ADD(p, ctrl)                                                      \
  p += __int_as_float(__builtin_amdgcn_update_dpp(                            \
      0, __float_as_int(p), ctrl, 0xF, 0xF, true));
// row_bcast15 (0x142): lane15 -> lanes16-31 (and 47 -> 48-63). After 4x ror,
// lanes 16..31 of each 32-lane row-group hold the full 32-lane sum.
#define BCAST15_ADD(p)                                                        \
  p += __int_as_float(__builtin_amdgcn_update_dpp(                            \
      0, __float_as_int(p), 0x142, 0xF, 0xF, true));

__global__ __launch_bounds__(256)
void bdh_seq_kernel(const float* __restrict__ x,
                    const float* __restrict__ w_init,
                    const float* __restrict__ alpha_p,
                    const float* __restrict__ eta_p,
                    const int*   __restrict__ mask,
                    float* __restrict__ out)
{
    const int tid  = threadIdx.x;
    const int bidx = blockIdx.x;           // 512 blocks
    const int b      = bidx & 31;          // batch; %8 pins batch to one XCD L2
    const int i_base = (bidx >> 5) << 3;   // 8 rows per block
    const int rloc   = tid >> 5;           // 0..7 (32 lanes per row)
    const int i      = i_base + rloc;
    const int cg     = tid & 31;
    const int j0     = cg << 2;            // 4 cols per lane

    __shared__ float ybuf[YB][8];

    const float alpha = alpha_p[0];
    const float eta   = eta_p[0];

    const float* xb = x + (size_t)b * TT * NN;
    const int*   mb = mask + b * TT;

    float* wout = out + ((size_t)b * NN + i) * NN + j0;
    float* yout = out + (size_t)BB * NN * NN + (size_t)b * TT * NN;

    float4 w = *reinterpret_cast<const float4*>(
        w_init + ((size_t)b * NN + i) * NN + j0);

    // Double-buffered 8-step groups: loads issued one full group ahead.
    float4 Xc[8], Xn[8];
    float  xic[8], xin[8];
    int    mc[8],  mn[8];
    float  p[16];

#define LOADG(X, XI, M, tbase)                                                \
  {                                                                           \
    const float* gp = xb + (size_t)(tbase) * NN;                              \
    _Pragma("unroll")                                                         \
    for (int k = 0; k < 8; ++k) {                                             \
      X[k]  = *reinterpret_cast<const float4*>(gp + k * NN + j0);             \
      XI[k] = gp[k * NN + i];                                                 \
    }                                                                         \
    *reinterpret_cast<int4*>(&M[0]) =                                         \
        *reinterpret_cast<const int4*>(mb + (tbase));                         \
    *reinterpret_cast<int4*>(&M[4]) =                                         \
        *reinterpret_cast<const int4*>(mb + (tbase) + 4);                     \
  }

// Dot (reads w) + masked Hebbian update. Reduce deferred to batched phase.
#define COMPG(X, XI, M, pbase)                                                \
  {                                                                           \
    _Pragma("unroll")                                                         \
    for (int k = 0; k < 8; ++k) {                                             \
      const float aa = M[k] ? alpha : 1.0f;                                   \
      const float ci = (M[k] ? eta : 0.0f) * XI[k];                           \
      float p0 = fmaf(w.y, X[k].y, w.x * X[k].x);                             \
      float p1 = fmaf(w.w, X[k].w, w.z * X[k].z);                             \
      p[(pbase) + k] = p0 + p1;                                               \
      w.x = fmaf(aa, w.x, ci * X[k].x);                                       \
      w.y = fmaf(aa, w.y, ci * X[k].y);                                       \
      w.z = fmaf(aa, w.z, ci * X[k].z);                                       \
      w.w = fmaf(aa, w.w, ci * X[k].w);                                       \
    }                                                                         \
  }

    LOADG(Xc, xic, mc, 0);
    LOADG(Xn, xin, mn, 8);

#pragma unroll 1
    for (int t = 0; t < TT; t += 16) {
        COMPG(Xc, xic, mc, 0);
        if (t + 16 < TT) LOADG(Xc, xic, mc, t + 16);   // prefetch next-next
        COMPG(Xn, xin, mn, 8);
        if (t + 24 < TT) LOADG(Xn, xin, mn, t + 24);

        // 16 independent reduce chains, stage-outer -> full DPP ILP.
        // Literal DPP ctrls per stage (builtin requires constant integer).
#pragma unroll
        for (int k = 0; k < 16; ++k) { ROR_ADD(p[k], 0x121); }
#pragma unroll
        for (int k = 0; k < 16; ++k) { ROR_ADD(p[k], 0x122); }
#pragma unroll
        for (int k = 0; k < 16; ++k) { ROR_ADD(p[k], 0x124); }
#pragma unroll
        for (int k = 0; k < 16; ++k) { ROR_ADD(p[k], 0x128); }
#pragma unroll
        for (int k = 0; k < 16; ++k) { BCAST15_ADD(p[k]); }

        if (cg == 16) {
#pragma unroll
            for (int k = 0; k < 16; ++k)
                ybuf[(t + k) & (YB - 1)][rloc] = p[k];
        }

        // Flush 256 buffered y steps with coalesced stores (4x per kernel).
        if (((t + 16) & (YB - 1)) == 0) {
            __syncthreads();
            const int t0 = t + 16 - YB;
#pragma unroll
            for (int pass = 0; pass < 8; ++pass) {
                const int tq = (tid >> 3) + (pass << 5);
                const int il = tid & 7;
                yout[(size_t)(t0 + tq) * NN + i_base + il] = ybuf[tq][il];
            }
            __syncthreads();
        }
    }
#undef LOADG
#undef COMPG

    *reinterpret_cast<float4*>(wout) = w;
}

extern "C" void kernel_launch(void* const* d_in, const int* in_sizes, int n_in,
                              void* d_out, int out_size, void* d_ws, size_t ws_size,
                              hipStream_t stream)
{
    const float* x      = (const float*)d_in[0];
    const float* w_init = (const float*)d_in[1];
    const float* alpha  = (const float*)d_in[2];
    const float* eta    = (const float*)d_in[3];
    const int*   mask   = (const int*)d_in[4];
    float*       out    = (float*)d_out;

    dim3 grid(512), block(256);
    hipLaunchKernelGGL(bdh_seq_kernel, grid, block, 0, stream,
                       x, w_init, alpha, eta, mask, out);
}